// Round 4
// baseline (358.913 us; speedup 1.0000x reference)
//
#include <hip/hip_runtime.h>
#include <math.h>

namespace {

constexpr int MAXM = 132;  // padded max bin count (final M = 129)
constexpr int RPB  = 4;    // rays per block (one ray per 64-lane wave)

// ---- DPP helpers (gfx9-family encodings, valid on CDNA4) ----
template <int CTRL, int ROW_MASK>
__device__ __forceinline__ float dpp_f(float x, float oldv) {
  union { float f; int i; } a, b, r;
  a.f = x; b.f = oldv;
  r.i = __builtin_amdgcn_update_dpp(b.i, a.i, CTRL, ROW_MASK, 0xf, false);
  return r.f;
}

__device__ __forceinline__ float readlane_f(float x, int l) {
  union { float f; int i; } a, r;
  a.f = x;
  r.i = __builtin_amdgcn_readlane(a.i, l);
  return r.f;
}

// 64-lane inclusive scans, pure VALU (no DS ops)
__device__ __forceinline__ float scan_mul_dpp(float v) {
  v *= dpp_f<0x111, 0xf>(v, 1.0f);
  v *= dpp_f<0x112, 0xf>(v, 1.0f);
  v *= dpp_f<0x114, 0xf>(v, 1.0f);
  v *= dpp_f<0x118, 0xf>(v, 1.0f);
  v *= dpp_f<0x142, 0xa>(v, 1.0f);  // row_bcast:15 -> rows 1,3
  v *= dpp_f<0x143, 0xc>(v, 1.0f);  // row_bcast:31 -> rows 2,3
  return v;
}

__device__ __forceinline__ float scan_add_dpp(float v) {
  v += dpp_f<0x111, 0xf>(v, 0.0f);
  v += dpp_f<0x112, 0xf>(v, 0.0f);
  v += dpp_f<0x114, 0xf>(v, 0.0f);
  v += dpp_f<0x118, 0xf>(v, 0.0f);
  v += dpp_f<0x142, 0xa>(v, 0.0f);
  v += dpp_f<0x143, 0xc>(v, 0.0f);
  return v;
}

__device__ __forceinline__ float rcpf(float x) { return __builtin_amdgcn_rcpf(x); }
__device__ __forceinline__ void wbar() { __builtin_amdgcn_wave_barrier(); }

__global__ __launch_bounds__(RPB * 64, 8) void neus_sampler(
    const float* __restrict__ org, const float* __restrict__ dirp,
    const float* __restrict__ nearp, const float* __restrict__ farp,
    float* __restrict__ out, int R) {
  __shared__ float sbA[RPB][MAXM], sdA[RPB][MAXM];
  __shared__ float sbB[RPB][MAXM], sdB[RPB][MAXM];
  __shared__ float cdfS[RPB][MAXM];

  const int wave = threadIdx.x >> 6;
  const int lane = threadIdx.x & 63;
  int ray = blockIdx.x * RPB + wave;
  const bool live = ray < R;
  if (!live) ray = R - 1;

  const float ox = org[3 * ray + 0], oy = org[3 * ray + 1], oz = org[3 * ray + 2];
  const float dx = dirp[3 * ray + 0], dy = dirp[3 * ray + 1], dz = dirp[3 * ray + 2];
  const float nr = nearp[ray], fr = farp[ray];
  const float fmn = fr - nr;

  float* sb  = sbA[wave];
  float* sd  = sdA[wave];
  float* sb2 = sbB[wave];
  float* sd2 = sdB[wave];
  float* cd  = cdfS[wave];

  // ---- init: sbins = linspace(0,1,65); sdf at the 64 starts ----
  for (int i = lane; i < 65; i += 64) sb[i] = (float)i * (1.0f / 64.0f);
  {
    float s = (float)lane * (1.0f / 64.0f);
    float e = nr + s * fmn;
    float px = ox + dx * e, py = oy + dy * e, pz = oz + dz * e;
    sd[lane] = sqrtf(px * px + py * py + pz * pz) - 1.0f;
  }
  wbar();

  int M = 65;
#pragma unroll 1
  for (int it = 0; it < 4; ++it) {
    const float inv_s = 64.0f * (float)(1 << it);
    const bool has1 = (M > 66);     // chunk 1 live (it >= 1)
    const int m1ok = M - 66;        // chunk-1 lane validity bound

    // ---- phase A: alphas, transmittance (DPP cumprod), raw-weight cumsum ----
    // chunk registers kept live through the merge (used by ballot ranking)
    float sA0, sA1, dA0, dA1;       // sb[i], sb[i+64], sd[i], sd[i+64]
    float cum0 = 0.0f, cum1 = 0.0f, carryS = 0.0f;
    float carryT, cos_carry;
    {
      int i = lane;
      bool act = (i <= M - 3);
      sA0 = sb[i];
      float s1v = sb[i + 1];
      dA0 = sd[i];
      float sd1 = sd[i + 1];
      float delta = (s1v - sA0) * fmn;
      float cosv = (sd1 - dA0) * rcpf(delta + 1e-5f);
      cos_carry = readlane_f(cosv, 63);
      float cosp = dpp_f<0x138, 0xf>(cosv, 0.0f);  // wave_shr:1, lane0 -> 0
      float cv = fmaxf(fminf(fminf(cosp, cosv), 0.0f), -1000.0f);
      float mid = 0.5f * (dA0 + sd1);
      float hd = cv * delta * 0.5f;
      float pc = rcpf(1.0f + __expf(-(mid - hd) * inv_s));
      float nc = rcpf(1.0f + __expf(-(mid + hd) * inv_s));
      float a = (pc - nc + 1e-5f) * rcpf(pc + 1e-5f);
      float alpha = act ? a : 0.0f;
      float q = act ? (1.0f - alpha + 1e-7f) : 1.0f;
      float S = scan_mul_dpp(q);
      float T = dpp_f<0x138, 0xf>(S, 1.0f);
      carryT = readlane_f(S, 63);
      float wv = alpha * T;
      float Sw = scan_add_dpp(wv);
      cum0 = Sw;
      carryS = readlane_f(Sw, 63);
    }
    sA1 = 0.0f; dA1 = 0.0f;
    if (has1) {
      int i = lane + 64;
      bool act = (i <= M - 3);
      sA1 = sb[i];
      float s1v = sb[i + 1];
      dA1 = sd[i];
      float sd1 = sd[i + 1];
      float delta = (s1v - sA1) * fmn;
      float cosv = (sd1 - dA1) * rcpf(delta + 1e-5f);
      float cosp = dpp_f<0x138, 0xf>(cosv, cos_carry);
      float cv = fmaxf(fminf(fminf(cosp, cosv), 0.0f), -1000.0f);
      float mid = 0.5f * (dA1 + sd1);
      float hd = cv * delta * 0.5f;
      float pc = rcpf(1.0f + __expf(-(mid - hd) * inv_s));
      float nc = rcpf(1.0f + __expf(-(mid + hd) * inv_s));
      float a = (pc - nc + 1e-5f) * rcpf(pc + 1e-5f);
      float alpha = act ? a : 0.0f;
      float q = act ? (1.0f - alpha + 1e-7f) : 1.0f;
      float S = scan_mul_dpp(q);
      float T = carryT * dpp_f<0x138, 0xf>(S, 1.0f);
      float wv = alpha * T;
      float Sw = scan_add_dpp(wv);
      cum1 = carryS + Sw;
      carryS += readlane_f(Sw, 63);
    }

    // padding + normalization folded into the cdf transform
    float wsum = carryS;
    float pad = fmaxf(1e-5f - wsum, 0.0f);
    float wadd = pad / (float)(M - 1);
    float rw = rcpf(wsum + pad);

    // cdf values in registers; mirrored to LDS for the 4-point gathers
    float cdv0 = fminf(1.0f, (cum0 + (float)(lane + 1) * wadd) * rw);
    float cdv1 = 2.0f;
    cd[lane + 1] = cdv0;
    if (has1 && lane <= m1ok) {
      int i = lane + 64;
      cdv1 = fminf(1.0f, (cum1 + (float)(i + 1) * wadd) * rw);
      cd[i + 1] = cdv1;
    }
    if (lane == 0) cd[0] = 0.0f;
    wbar();

    // ---- phase B: searchsorted via ballot ranking (no serial LDS chain) ----
    int inds = 0;
#pragma unroll
    for (int j = 0; j < 17; ++j) {
      const float uj = (float)((double)j * ((1.0 - 1.0 / 17.0) / 16.0)) +
                       (float)(1.0 / 34.0);
      unsigned long long b0 = __ballot(cdv0 <= uj);  // cd[1..64], all valid
      int c = 1 + __popcll(b0);                      // +1 for cd[0]=0 <= u
      if (has1) {
        unsigned long long b1 = __ballot((lane <= m1ok) && (cdv1 <= uj));
        c += __popcll(b1);
      }
      if (lane == j) inds = c;  // uniform value -> cndmask "writelane"
    }

    float newbin = 0.0f;
    if (lane < 17) {
      float u = (float)((double)lane * ((1.0 - 1.0 / 17.0) / 16.0)) +
                (float)(1.0 / 34.0);
      int below = inds - 1;
      if (below < 0) below = 0;
      if (below > M - 1) below = M - 1;
      int above = inds;
      if (above > M - 1) above = M - 1;
      float c0 = cd[below], c1 = cd[above];
      float b0v = sb[below], b1v = sb[above];
      float den = c1 - c0;
      den = (den < 1e-5f) ? 1.0f : den;
      float t = fminf(fmaxf((u - c0) * rcpf(den), 0.0f), 1.0f);
      newbin = b0v + t * (b1v - b0v);
    }

    // ---- phase C: stable merge via ballot ranks (old first on ties) ----
    float nb16 = readlane_f(newbin, 16);
    int cnt0 = 0, cnt1 = 0, myLo = 0;
#pragma unroll
    for (int j = 0; j < 16; ++j) {
      float nbj = readlane_f(newbin, j);
      cnt0 += (nbj < sA0) ? 1 : 0;
      int lo = __popcll(__ballot(sA0 <= nbj));  // old starts 0..63, all valid
      if (has1) {
        cnt1 += (nbj < sA1) ? 1 : 0;
        lo += __popcll(__ballot((lane <= m1ok) && (sA1 <= nbj)));
      }
      if (lane == j) myLo = lo;  // uniform value -> cndmask "writelane"
    }
    {  // old elements, chunk 0 (i = lane, always <= M-2)
      int pos = lane + cnt0;
      sb2[pos] = sA0;
      if (it != 3) sd2[pos] = dA0;
    }
    if (has1 && lane <= m1ok) {  // old elements, chunk 1
      int pos = lane + 64 + cnt1;
      sb2[pos] = sA1;
      if (it != 3) sd2[pos] = dA1;
    }
    if (lane < 16) {  // new elements
      int pos = lane + myLo;
      sb2[pos] = newbin;
      if (it != 3) {
        float e = nr + newbin * fmn;
        float px = ox + dx * e, py = oy + dy * e, pz = oz + dz * e;
        sd2[pos] = sqrtf(px * px + py * py + pz * pz) - 1.0f;
      }
    }
    if (lane == 0) sb2[M + 15] = fmaxf(sb[M - 1], nb16);
    wbar();
    {
      float* t = sb; sb = sb2; sb2 = t;
      t = sd; sd = sd2; sd2 = t;
    }
    M += 16;
  }

  // ---- final: out[ray, i, :], i<128; 3x float2 per lane (coalesced) ----
  if (live) {
    float s0 = sb[2 * lane], s1 = sb[2 * lane + 1];
    float e0 = nr + s0 * fmn, e1 = nr + s1 * fmn;
    float ax = ox + dx * e0, ay = oy + dy * e0, az = oz + dz * e0;
    float bx = ox + dx * e1, by = oy + dy * e1, bz = oz + dz * e1;
    float2* o = (float2*)(out + (size_t)ray * 384 + (size_t)lane * 6);
    o[0] = make_float2(ax, ay);
    o[1] = make_float2(az, bx);
    o[2] = make_float2(by, bz);
  }
}

}  // namespace

extern "C" void kernel_launch(void* const* d_in, const int* in_sizes, int n_in,
                              void* d_out, int out_size, void* d_ws, size_t ws_size,
                              hipStream_t stream) {
  const float* org  = (const float*)d_in[0];
  const float* dirp = (const float*)d_in[1];
  const float* nrp  = (const float*)d_in[2];
  const float* frp  = (const float*)d_in[3];
  float* out = (float*)d_out;
  const int R = in_sizes[0] / 3;
  const int grid = (R + RPB - 1) / RPB;
  hipLaunchKernelGGL(neus_sampler, dim3(grid), dim3(RPB * 64), 0, stream,
                     org, dirp, nrp, frp, out, R);
}

// Round 5
// 210.392 us; speedup vs baseline: 1.7059x; 1.7059x over previous
//
#include <hip/hip_runtime.h>
#include <math.h>

namespace {

constexpr int MAXM = 132;  // padded max bin count (final M = 129)
constexpr int RPB  = 4;    // rays per block (one ray per 64-lane wave)

// ---- DPP helpers (gfx9-family encodings, valid on CDNA4) ----
template <int CTRL, int ROW_MASK>
__device__ __forceinline__ float dpp_f(float x, float oldv) {
  union { float f; int i; } a, b, r;
  a.f = x; b.f = oldv;
  r.i = __builtin_amdgcn_update_dpp(b.i, a.i, CTRL, ROW_MASK, 0xf, false);
  return r.f;
}

template <int CTRL, int ROW_MASK>
__device__ __forceinline__ int dpp_i(int x, int oldv) {
  return __builtin_amdgcn_update_dpp(oldv, x, CTRL, ROW_MASK, 0xf, false);
}

__device__ __forceinline__ float readlane_f(float x, int l) {
  union { float f; int i; } a, r;
  a.f = x;
  r.i = __builtin_amdgcn_readlane(a.i, l);
  return r.f;
}

// 64-lane inclusive scans, pure VALU (no DS ops)
__device__ __forceinline__ float scan_mul_dpp(float v) {
  v *= dpp_f<0x111, 0xf>(v, 1.0f);
  v *= dpp_f<0x112, 0xf>(v, 1.0f);
  v *= dpp_f<0x114, 0xf>(v, 1.0f);
  v *= dpp_f<0x118, 0xf>(v, 1.0f);
  v *= dpp_f<0x142, 0xa>(v, 1.0f);  // row_bcast:15 -> rows 1,3
  v *= dpp_f<0x143, 0xc>(v, 1.0f);  // row_bcast:31 -> rows 2,3
  return v;
}

__device__ __forceinline__ float scan_add_dpp(float v) {
  v += dpp_f<0x111, 0xf>(v, 0.0f);
  v += dpp_f<0x112, 0xf>(v, 0.0f);
  v += dpp_f<0x114, 0xf>(v, 0.0f);
  v += dpp_f<0x118, 0xf>(v, 0.0f);
  v += dpp_f<0x142, 0xa>(v, 0.0f);
  v += dpp_f<0x143, 0xc>(v, 0.0f);
  return v;
}

__device__ __forceinline__ int scan_max_dpp(int v) {
  v = max(v, dpp_i<0x111, 0xf>(v, 0));
  v = max(v, dpp_i<0x112, 0xf>(v, 0));
  v = max(v, dpp_i<0x114, 0xf>(v, 0));
  v = max(v, dpp_i<0x118, 0xf>(v, 0));
  v = max(v, dpp_i<0x142, 0xa>(v, 0));
  v = max(v, dpp_i<0x143, 0xc>(v, 0));
  return v;
}

__device__ __forceinline__ float rcpf(float x) { return __builtin_amdgcn_rcpf(x); }
__device__ __forceinline__ void wbar() { __builtin_amdgcn_wave_barrier(); }

__global__ __launch_bounds__(RPB * 64, 8) void neus_sampler(
    const float* __restrict__ org, const float* __restrict__ dirp,
    const float* __restrict__ nearp, const float* __restrict__ farp,
    float* __restrict__ out, int R) {
  __shared__ float sbA[RPB][MAXM], sdA[RPB][MAXM];
  __shared__ float sbB[RPB][MAXM], sdB[RPB][MAXM];
  __shared__ float cdfS[RPB][MAXM];
  __shared__ int   cbS[RPB][MAXM];   // phase-C rank board (129 cells)
  __shared__ int   bdS[RPB][20];     // phase-B bucket board (17 cells)

  const int wave = threadIdx.x >> 6;
  const int lane = threadIdx.x & 63;
  int ray = blockIdx.x * RPB + wave;
  const bool live = ray < R;
  if (!live) ray = R - 1;

  const float ox = org[3 * ray + 0], oy = org[3 * ray + 1], oz = org[3 * ray + 2];
  const float dx = dirp[3 * ray + 0], dy = dirp[3 * ray + 1], dz = dirp[3 * ray + 2];
  const float nr = nearp[ray], fr = farp[ray];
  const float fmn = fr - nr;

  float* sb  = sbA[wave];
  float* sd  = sdA[wave];
  float* sb2 = sbB[wave];
  float* sd2 = sdB[wave];
  float* cd  = cdfS[wave];
  int*   cb  = cbS[wave];
  int*   bd  = bdS[wave];

  // ---- init: sbins = linspace(0,1,65); sdf at the 64 starts ----
  for (int i = lane; i < 65; i += 64) sb[i] = (float)i * (1.0f / 64.0f);
  {
    float s = (float)lane * (1.0f / 64.0f);
    float e = nr + s * fmn;
    float px = ox + dx * e, py = oy + dy * e, pz = oz + dz * e;
    sd[lane] = sqrtf(px * px + py * py + pz * pz) - 1.0f;
  }
  wbar();

  int M = 65;
#pragma unroll 1
  for (int it = 0; it < 4; ++it) {
    const float inv_s = 64.0f * (float)(1 << it);
    const bool has1 = (M > 66);     // chunk 1 live (it >= 1)
    const int m1ok = M - 66;        // chunk-1 lane validity bound

    // ---- phase A: alphas, transmittance (DPP cumprod), raw-weight cumsum ----
    float sA0, sA1, dA0, dA1;       // sb[i], sb[i+64], sd[i], sd[i+64]
    float cum0 = 0.0f, cum1 = 0.0f, carryS = 0.0f;
    float carryT, cos_carry;
    {
      int i = lane;
      bool act = (i <= M - 3);
      sA0 = sb[i];
      float s1v = sb[i + 1];
      dA0 = sd[i];
      float sd1 = sd[i + 1];
      float delta = (s1v - sA0) * fmn;
      float cosv = (sd1 - dA0) * rcpf(delta + 1e-5f);
      cos_carry = readlane_f(cosv, 63);
      float cosp = dpp_f<0x138, 0xf>(cosv, 0.0f);  // wave_shr:1, lane0 -> 0
      float cv = fmaxf(fminf(fminf(cosp, cosv), 0.0f), -1000.0f);
      float mid = 0.5f * (dA0 + sd1);
      float hd = cv * delta * 0.5f;
      // alpha = ((b-a)/(1+b) + eps(1+a)) / (1 + eps(1+a)),  a=e^{-pe*s}, b=e^{-ne*s}
      float ea = __expf(fminf((hd - mid) * inv_s, 80.0f));
      float eb = __expf(fminf(-(mid + hd) * inv_s, 80.0f));
      float t5 = 1e-5f * (1.0f + ea);
      float a = ((eb - ea) * rcpf(1.0f + eb) + t5) * rcpf(1.0f + t5);
      float alpha = act ? a : 0.0f;
      float q = act ? (1.0f - alpha + 1e-7f) : 1.0f;
      float S = scan_mul_dpp(q);
      float T = dpp_f<0x138, 0xf>(S, 1.0f);
      carryT = readlane_f(S, 63);
      float wv = alpha * T;
      float Sw = scan_add_dpp(wv);
      cum0 = Sw;
      carryS = readlane_f(Sw, 63);
    }
    sA1 = 0.0f; dA1 = 0.0f;
    if (has1) {
      int i = lane + 64;
      bool act = (i <= M - 3);
      sA1 = sb[i];
      float s1v = sb[i + 1];
      dA1 = sd[i];
      float sd1 = sd[i + 1];
      float delta = (s1v - sA1) * fmn;
      float cosv = (sd1 - dA1) * rcpf(delta + 1e-5f);
      float cosp = dpp_f<0x138, 0xf>(cosv, cos_carry);
      float cv = fmaxf(fminf(fminf(cosp, cosv), 0.0f), -1000.0f);
      float mid = 0.5f * (dA1 + sd1);
      float hd = cv * delta * 0.5f;
      float ea = __expf(fminf((hd - mid) * inv_s, 80.0f));
      float eb = __expf(fminf(-(mid + hd) * inv_s, 80.0f));
      float t5 = 1e-5f * (1.0f + ea);
      float a = ((eb - ea) * rcpf(1.0f + eb) + t5) * rcpf(1.0f + t5);
      float alpha = act ? a : 0.0f;
      float q = act ? (1.0f - alpha + 1e-7f) : 1.0f;
      float S = scan_mul_dpp(q);
      float T = carryT * dpp_f<0x138, 0xf>(S, 1.0f);
      float wv = alpha * T;
      float Sw = scan_add_dpp(wv);
      cum1 = carryS + Sw;
      carryS += readlane_f(Sw, 63);
    }

    // padding + normalization folded into the cdf transform
    float wsum = carryS;
    float pad = fmaxf(1e-5f - wsum, 0.0f);
    float wadd = pad / (float)(M - 1);
    float rw = rcpf(wsum + pad);

    // cdf values in registers; mirrored to LDS for the interp gathers
    float cdv0 = fminf(1.0f, (cum0 + (float)(lane + 1) * wadd) * rw);
    float cdv1 = 2.0f;
    cd[lane + 1] = cdv0;
    if (has1 && lane <= m1ok) {
      int i = lane + 64;
      cdv1 = fminf(1.0f, (cum1 + (float)(i + 1) * wadd) * rw);
      cd[i + 1] = cdv1;
    }
    if (lane == 0) cd[0] = 0.0f;
    // zero the phase-B bucket board while cdf settles
    if (lane < 17) bd[lane] = 0;
    wbar();

    // ---- phase B: searchsorted via bucket-scatter + 17-lane max-scan ----
    // element i (cd index) scatters i into bucket jmin = ceil(17*cdf_i - 0.5);
    // highest lane (= largest i) wins; inds_j = 1 + maxscan(board)_j.
    {
      int jm = (int)ceilf(cdv0 * 17.0f - 0.5f);
      if (jm < 17) { if (jm < 0) jm = 0; bd[jm] = lane + 1; }
    }
    if (has1) {
      int jm = (int)ceilf(cdv1 * 17.0f - 0.5f);  // invalid lanes: cdv1=2 -> masked
      if (jm < 17) { if (jm < 0) jm = 0; bd[jm] = lane + 65; }
    }
    // zero the phase-C rank board in the same window
    cb[lane] = 0;
    cb[lane + 64] = 0;
    wbar();

    int inds = 0;
    {
      int h = (lane < 17) ? bd[lane] : 0;
      h = max(h, dpp_i<0x111, 0xf>(h, 0));
      h = max(h, dpp_i<0x112, 0xf>(h, 0));
      h = max(h, dpp_i<0x114, 0xf>(h, 0));
      h = max(h, dpp_i<0x118, 0xf>(h, 0));
      int s15 = __builtin_amdgcn_readlane(h, 15);
      if (lane == 16) h = max(h, s15);  // lane16 crosses the row boundary
      inds = 1 + h;
    }

    // ---- interp + closed-form merge rank for new bins ----
    float newbin = 0.0f;
    int lo = 0;
    if (lane < 17) {
      float u = (float)((double)lane * ((1.0 - 1.0 / 17.0) / 16.0)) +
                (float)(1.0 / 34.0);
      int below = inds - 1;
      if (below < 0) below = 0;
      if (below > M - 1) below = M - 1;
      int above = inds;
      if (above > M - 1) above = M - 1;
      float c0 = cd[below], c1 = cd[above];
      float b0v = sb[below], b1v = sb[above];
      float den = c1 - c0;
      den = (den < 1e-5f) ? 1.0f : den;
      float t = fminf(fmaxf((u - c0) * rcpf(den), 0.0f), 1.0f);
      newbin = b0v + t * (b1v - b0v);
      // upper_bound(sb[0..M-2], newbin) without a search:
      // sb[below] <= newbin <= sb[above]; +1 iff equal to a real start
      lo = above;
      if (newbin == b1v && above <= M - 2) lo = above + 1;
    }
    float nb16 = readlane_f(newbin, 16);

    // scatter new-bin ranks: cell lo_j <- j+1 (highest j wins on collision)
    if (lane < 16) cb[lo] = lane + 1;
    wbar();

    // ---- phase C: old-element shifts via 129-cell max-scan ----
    int m0 = cb[lane];
    int m1 = has1 ? cb[lane + 64] : 0;
    int c0s = scan_max_dpp(m0);
    int carryC = __builtin_amdgcn_readlane(c0s, 63);
    int c1s = max(scan_max_dpp(m1), carryC);

    {  // old elements, chunk 0 (i = lane, always <= M-2)
      int pos = lane + c0s;
      sb2[pos] = sA0;
      if (it != 3) sd2[pos] = dA0;
    }
    if (has1 && lane <= m1ok) {  // old elements, chunk 1
      int pos = lane + 64 + c1s;
      sb2[pos] = sA1;
      if (it != 3) sd2[pos] = dA1;
    }
    if (lane < 16) {  // new elements at j + lo_j
      int pos = lane + lo;
      sb2[pos] = newbin;
      if (it != 3) {
        float e = nr + newbin * fmn;
        float px = ox + dx * e, py = oy + dy * e, pz = oz + dz * e;
        sd2[pos] = sqrtf(px * px + py * py + pz * pz) - 1.0f;
      }
    }
    if (lane == 0) sb2[M + 15] = fmaxf(sb[M - 1], nb16);
    wbar();
    {
      float* t = sb; sb = sb2; sb2 = t;
      t = sd; sd = sd2; sd2 = t;
    }
    M += 16;
  }

  // ---- final: out[ray, i, :], i<128; 3x float2 per lane (coalesced) ----
  if (live) {
    float s0 = sb[2 * lane], s1 = sb[2 * lane + 1];
    float e0 = nr + s0 * fmn, e1 = nr + s1 * fmn;
    float ax = ox + dx * e0, ay = oy + dy * e0, az = oz + dz * e0;
    float bx = ox + dx * e1, by = oy + dy * e1, bz = oz + dz * e1;
    float2* o = (float2*)(out + (size_t)ray * 384 + (size_t)lane * 6);
    o[0] = make_float2(ax, ay);
    o[1] = make_float2(az, bx);
    o[2] = make_float2(by, bz);
  }
}

}  // namespace

extern "C" void kernel_launch(void* const* d_in, const int* in_sizes, int n_in,
                              void* d_out, int out_size, void* d_ws, size_t ws_size,
                              hipStream_t stream) {
  const float* org  = (const float*)d_in[0];
  const float* dirp = (const float*)d_in[1];
  const float* nrp  = (const float*)d_in[2];
  const float* frp  = (const float*)d_in[3];
  float* out = (float*)d_out;
  const int R = in_sizes[0] / 3;
  const int grid = (R + RPB - 1) / RPB;
  hipLaunchKernelGGL(neus_sampler, dim3(grid), dim3(RPB * 64), 0, stream,
                     org, dirp, nrp, frp, out, R);
}

// Round 7
// 179.931 us; speedup vs baseline: 1.9947x; 1.1693x over previous
//
#include <hip/hip_runtime.h>
#include <math.h>

namespace {

constexpr int MAXM = 132;  // padded max bin count (final M = 129)
constexpr int RPB  = 4;    // rays per block (one ray per 64-lane wave)

// ---- DPP helpers (gfx9-family encodings, valid on CDNA4) ----
template <int CTRL, int ROW_MASK>
__device__ __forceinline__ float dpp_f(float x, float oldv) {
  union { float f; int i; } a, b, r;
  a.f = x; b.f = oldv;
  r.i = __builtin_amdgcn_update_dpp(b.i, a.i, CTRL, ROW_MASK, 0xf, false);
  return r.f;
}

template <int CTRL, int ROW_MASK>
__device__ __forceinline__ int dpp_i(int x, int oldv) {
  return __builtin_amdgcn_update_dpp(oldv, x, CTRL, ROW_MASK, 0xf, false);
}

__device__ __forceinline__ float readlane_f(float x, int l) {
  union { float f; int i; } a, r;
  a.f = x;
  r.i = __builtin_amdgcn_readlane(a.i, l);
  return r.f;
}

// 64-lane inclusive scans, pure VALU (no DS ops)
__device__ __forceinline__ float scan_mul_dpp(float v) {
  v *= dpp_f<0x111, 0xf>(v, 1.0f);
  v *= dpp_f<0x112, 0xf>(v, 1.0f);
  v *= dpp_f<0x114, 0xf>(v, 1.0f);
  v *= dpp_f<0x118, 0xf>(v, 1.0f);
  v *= dpp_f<0x142, 0xa>(v, 1.0f);  // row_bcast:15 -> rows 1,3
  v *= dpp_f<0x143, 0xc>(v, 1.0f);  // row_bcast:31 -> rows 2,3
  return v;
}

__device__ __forceinline__ float scan_add_dpp(float v) {
  v += dpp_f<0x111, 0xf>(v, 0.0f);
  v += dpp_f<0x112, 0xf>(v, 0.0f);
  v += dpp_f<0x114, 0xf>(v, 0.0f);
  v += dpp_f<0x118, 0xf>(v, 0.0f);
  v += dpp_f<0x142, 0xa>(v, 0.0f);
  v += dpp_f<0x143, 0xc>(v, 0.0f);
  return v;
}

__device__ __forceinline__ int scan_max_dpp(int v) {
  v = max(v, dpp_i<0x111, 0xf>(v, 0));
  v = max(v, dpp_i<0x112, 0xf>(v, 0));
  v = max(v, dpp_i<0x114, 0xf>(v, 0));
  v = max(v, dpp_i<0x118, 0xf>(v, 0));
  v = max(v, dpp_i<0x142, 0xa>(v, 0));
  v = max(v, dpp_i<0x143, 0xc>(v, 0));
  return v;
}

__device__ __forceinline__ float rcpf(float x) { return __builtin_amdgcn_rcpf(x); }
__device__ __forceinline__ void wbar() { __builtin_amdgcn_wave_barrier(); }

__global__ __launch_bounds__(RPB * 64, 8) void neus_sampler(
    const float* __restrict__ org, const float* __restrict__ dirp,
    const float* __restrict__ nearp, const float* __restrict__ farp,
    float* __restrict__ out, int R) {
  __shared__ float sbA[RPB][MAXM], sdA[RPB][MAXM];
  __shared__ float sbB[RPB][MAXM], sdB[RPB][MAXM];
  __shared__ float cdfS[RPB][MAXM];
  __shared__ int   cbS[RPB][MAXM];   // phase-C rank board (129 cells)
  __shared__ int   bdS[RPB][20];     // phase-B bucket board (17 cells)

  const int wave = threadIdx.x >> 6;
  const int lane = threadIdx.x & 63;
  int ray = blockIdx.x * RPB + wave;
  const bool live = ray < R;
  if (!live) ray = R - 1;

  const float ox = org[3 * ray + 0], oy = org[3 * ray + 1], oz = org[3 * ray + 2];
  const float dx = dirp[3 * ray + 0], dy = dirp[3 * ray + 1], dz = dirp[3 * ray + 2];
  const float nr = nearp[ray], fr = farp[ray];
  const float fmn = fr - nr;

  float* sbP[2] = {sbA[wave], sbB[wave]};
  float* sdP[2] = {sdA[wave], sdB[wave]};
  float* cd = cdfS[wave];
  int*   cb = cbS[wave];
  int*   bd = bdS[wave];

  // hoisted per-lane constants
  const bool is17 = lane < 17;
  const bool is16 = lane < 16;
  const float uval = (float)((double)lane * ((1.0 - 1.0 / 17.0) / 16.0)) +
                     (float)(1.0 / 34.0);

  // ---- init: sbins = linspace(0,1,65); sdf at the 64 starts ----
  {
    float* sb = sbP[0];
    float* sd = sdP[0];
    for (int i = lane; i < 65; i += 64) sb[i] = (float)i * (1.0f / 64.0f);
    float s = (float)lane * (1.0f / 64.0f);
    float e = nr + s * fmn;
    float px = ox + dx * e, py = oy + dy * e, pz = oz + dz * e;
    sd[lane] = sqrtf(px * px + py * py + pz * pz) - 1.0f;
  }
  wbar();

#pragma unroll
  for (int it = 0; it < 4; ++it) {
    const float inv_s = 64.0f * (float)(1 << it);
    const int M = 65 + 16 * it;       // compile-time under unroll
    const bool has1 = (it > 0);
    const int m1ok = M - 66;          // chunk-1 old-element lane bound
    const float rM1 = 1.0f / (float)(M - 1);
    float* sb  = sbP[it & 1];
    float* sd  = sdP[it & 1];
    float* sb2 = sbP[(it & 1) ^ 1];
    float* sd2 = sdP[(it & 1) ^ 1];

    // ---- phase A: alpha (R5 numerics), cumprod scan, exact weight cumsum ----
    float sA0, sA1 = 0.0f, dA0, dA1 = 0.0f;
    float cum0, cum1 = 0.0f, carryS;
    float carryT, cos_carry;
    {
      sA0 = sb[lane];
      float s1v = sb[lane + 1];
      dA0 = sd[lane];
      float sd1 = sd[lane + 1];
      float delta = (s1v - sA0) * fmn;
      float cosv = (sd1 - dA0) * rcpf(delta + 1e-5f);
      cos_carry = readlane_f(cosv, 63);
      float cosp = dpp_f<0x138, 0xf>(cosv, 0.0f);  // wave_shr:1, lane0 -> 0
      float cv = fmaxf(fminf(fminf(cosp, cosv), 0.0f), -1000.0f);
      float mid = 0.5f * (dA0 + sd1);
      float hd = cv * delta * 0.5f;
      float ea = __expf(fminf((hd - mid) * inv_s, 80.0f));
      float eb = __expf(fminf(-(mid + hd) * inv_s, 80.0f));
      float t5 = 1e-5f * (1.0f + ea);
      float a = ((eb - ea) * rcpf(1.0f + eb) + t5) * rcpf(1.0f + t5);
      float alpha, q;
      if (it == 0) {  // lanes > 62 are past the last alpha
        alpha = (lane <= 62) ? a : 0.0f;
        q = (lane <= 62) ? (1.0f - a + 1e-7f) : 1.0f;
      } else {        // all 64 chunk-0 intervals live
        alpha = a;
        q = 1.0f - a + 1e-7f;
      }
      float S = scan_mul_dpp(q);
      float T = dpp_f<0x138, 0xf>(S, 1.0f);  // exclusive cumprod
      carryT = readlane_f(S, 63);
      float wv = alpha * T;
      float Sw = scan_add_dpp(wv);
      cum0 = Sw;
      carryS = readlane_f(Sw, 63);
    }
    if (has1) {
      sA1 = sb[lane + 64];
      float s1v = sb[lane + 65];
      dA1 = sd[lane + 64];
      float sd1 = sd[lane + 65];
      float delta = (s1v - sA1) * fmn;
      float cosv = (sd1 - dA1) * rcpf(delta + 1e-5f);
      float cosp = dpp_f<0x138, 0xf>(cosv, cos_carry);
      float cv = fmaxf(fminf(fminf(cosp, cosv), 0.0f), -1000.0f);
      float mid = 0.5f * (dA1 + sd1);
      float hd = cv * delta * 0.5f;
      float ea = __expf(fminf((hd - mid) * inv_s, 80.0f));
      float eb = __expf(fminf(-(mid + hd) * inv_s, 80.0f));
      float t5 = 1e-5f * (1.0f + ea);
      float a = ((eb - ea) * rcpf(1.0f + eb) + t5) * rcpf(1.0f + t5);
      bool act = (lane <= M - 67);   // compile-time bound: intervals i <= M-3
      float alpha = act ? a : 0.0f;
      float q = act ? (1.0f - a + 1e-7f) : 1.0f;
      float S = scan_mul_dpp(q);
      float T = carryT * dpp_f<0x138, 0xf>(S, 1.0f);
      float wv = alpha * T;
      float Sw = scan_add_dpp(wv);
      cum1 = carryS + Sw;
      carryS += readlane_f(Sw, 63);
    }
    float wsum = carryS;
    float pad = fmaxf(1e-5f - wsum, 0.0f);
    float wadd = pad * rM1;
    float rw = rcpf(wsum + pad);

    // cdf cells: cd[i+1] = min(1, (cum_i + (i+1)*wadd) * rw)
    float cdv0 = fminf(1.0f, (cum0 + (float)(lane + 1) * wadd) * rw);
    cd[lane + 1] = cdv0;
    float cdv1 = 2.0f;
    if (has1) {
      cdv1 = fminf(1.0f, (cum1 + (float)(lane + 65) * wadd) * rw);
      cd[lane + 65] = cdv1;  // lanes > m1ok hit cells > M-1: never read
    }
    if (lane == 0) cd[0] = 0.0f;
    if (is17) bd[lane] = 0;
    wbar();

    // ---- phase B: searchsorted via bucket-scatter + 17-lane max-scan ----
    {
      int jm = (int)ceilf(cdv0 * 17.0f - 0.5f);
      if (jm < 17) { if (jm < 0) jm = 0; bd[jm] = lane + 1; }
    }
    if (has1) {
      int jm = (int)ceilf(cdv1 * 17.0f - 0.5f);
      if (lane <= m1ok && jm < 17) { if (jm < 0) jm = 0; bd[jm] = lane + 65; }
    }
    cb[lane] = 0;
    cb[lane + 64] = 0;
    wbar();

    int inds;
    {
      int h = is17 ? bd[lane] : 0;
      h = max(h, dpp_i<0x111, 0xf>(h, 0));
      h = max(h, dpp_i<0x112, 0xf>(h, 0));
      h = max(h, dpp_i<0x114, 0xf>(h, 0));
      h = max(h, dpp_i<0x118, 0xf>(h, 0));
      int s15 = __builtin_amdgcn_readlane(h, 15);
      if (lane == 16) h = max(h, s15);  // lane16 crosses the row boundary
      inds = 1 + h;                     // provably in [1, M-1]
    }

    // ---- interp + closed-form merge rank for new bins ----
    float newbin = 0.0f;
    int lo = 0;
    if (is17) {
      int below = inds - 1;             // adjacent pair, no clamps needed
      float c0 = cd[below], c1 = cd[inds];
      float b0v = sb[below], b1v = sb[inds];
      float den = c1 - c0;
      den = (den < 1e-5f) ? 1.0f : den;
      float t = fminf(fmaxf((uval - c0) * rcpf(den), 0.0f), 1.0f);
      newbin = b0v + t * (b1v - b0v);
      lo = inds;
      if (newbin == b1v && inds <= M - 2) lo = inds + 1;
    }
    float nb16 = readlane_f(newbin, 16);

    if (is16) cb[lo] = lane + 1;        // highest j wins on collision
    wbar();

    // ---- phase C: old-element shifts via 128-cell max-scan ----
    int m0 = cb[lane];
    int m1 = has1 ? cb[lane + 64] : 0;
    int c0s = scan_max_dpp(m0);
    int carryC = __builtin_amdgcn_readlane(c0s, 63);
    int c1s = max(scan_max_dpp(m1), carryC);

    {  // old elements, chunk 0 (i = lane, always <= M-2)
      int pos = lane + c0s;
      sb2[pos] = sA0;
      if (it != 3) sd2[pos] = dA0;
    }
    if (has1 && lane <= m1ok) {  // old elements, chunk 1
      int pos = lane + 64 + c1s;
      sb2[pos] = sA1;
      if (it != 3) sd2[pos] = dA1;
    }
    if (is16) {  // new elements at j + lo_j
      int pos = lane + lo;
      sb2[pos] = newbin;
      if (it != 3) {
        float e = nr + newbin * fmn;
        float px = ox + dx * e, py = oy + dy * e, pz = oz + dz * e;
        sd2[pos] = sqrtf(px * px + py * py + pz * pz) - 1.0f;
      }
    }
    if (lane == 0) sb2[M + 15] = fmaxf(sb[M - 1], nb16);
    wbar();
  }

  // ---- final: out[ray, i, :], i<128; 3x float2 per lane (coalesced) ----
  if (live) {
    float* sb = sbP[0];  // after 4 swaps, final bins are back in buffer 0
    float s0 = sb[2 * lane], s1 = sb[2 * lane + 1];
    float e0 = nr + s0 * fmn, e1 = nr + s1 * fmn;
    float ax = ox + dx * e0, ay = oy + dy * e0, az = oz + dz * e0;
    float bx = ox + dx * e1, by = oy + dy * e1, bz = oz + dz * e1;
    float2* o = (float2*)(out + (size_t)ray * 384 + (size_t)lane * 6);
    o[0] = make_float2(ax, ay);
    o[1] = make_float2(az, bx);
    o[2] = make_float2(by, bz);
  }
}

}  // namespace

extern "C" void kernel_launch(void* const* d_in, const int* in_sizes, int n_in,
                              void* d_out, int out_size, void* d_ws, size_t ws_size,
                              hipStream_t stream) {
  const float* org  = (const float*)d_in[0];
  const float* dirp = (const float*)d_in[1];
  const float* nrp  = (const float*)d_in[2];
  const float* frp  = (const float*)d_in[3];
  float* out = (float*)d_out;
  const int R = in_sizes[0] / 3;
  const int grid = (R + RPB - 1) / RPB;
  hipLaunchKernelGGL(neus_sampler, dim3(grid), dim3(RPB * 64), 0, stream,
                     org, dirp, nrp, frp, out, R);
}

// Round 8
// 175.227 us; speedup vs baseline: 2.0483x; 1.0268x over previous
//
#include <hip/hip_runtime.h>
#include <math.h>

namespace {

constexpr int MAXM = 132;  // padded max bin count (final M = 129)
constexpr int RPB  = 4;    // rays per block (one ray per 64-lane wave)

#if __has_builtin(__builtin_amdgcn_exp2f)
__device__ __forceinline__ float exp2_raw(float x) { return __builtin_amdgcn_exp2f(x); }
#else
__device__ __forceinline__ float exp2_raw(float x) { return exp2f(x); }
#endif

// ---- DPP helpers (gfx9-family encodings, valid on CDNA4) ----
template <int CTRL, int ROW_MASK>
__device__ __forceinline__ float dpp_f(float x, float oldv) {
  union { float f; int i; } a, b, r;
  a.f = x; b.f = oldv;
  r.i = __builtin_amdgcn_update_dpp(b.i, a.i, CTRL, ROW_MASK, 0xf, false);
  return r.f;
}

template <int CTRL, int ROW_MASK>
__device__ __forceinline__ int dpp_i(int x, int oldv) {
  return __builtin_amdgcn_update_dpp(oldv, x, CTRL, ROW_MASK, 0xf, false);
}

__device__ __forceinline__ float readlane_f(float x, int l) {
  union { float f; int i; } a, r;
  a.f = x;
  r.i = __builtin_amdgcn_readlane(a.i, l);
  return r.f;
}

// 64-lane inclusive scans, pure VALU (no DS ops)
__device__ __forceinline__ float scan_mul_dpp(float v) {
  v *= dpp_f<0x111, 0xf>(v, 1.0f);
  v *= dpp_f<0x112, 0xf>(v, 1.0f);
  v *= dpp_f<0x114, 0xf>(v, 1.0f);
  v *= dpp_f<0x118, 0xf>(v, 1.0f);
  v *= dpp_f<0x142, 0xa>(v, 1.0f);  // row_bcast:15 -> rows 1,3
  v *= dpp_f<0x143, 0xc>(v, 1.0f);  // row_bcast:31 -> rows 2,3
  return v;
}

__device__ __forceinline__ float scan_add_dpp(float v) {
  v += dpp_f<0x111, 0xf>(v, 0.0f);
  v += dpp_f<0x112, 0xf>(v, 0.0f);
  v += dpp_f<0x114, 0xf>(v, 0.0f);
  v += dpp_f<0x118, 0xf>(v, 0.0f);
  v += dpp_f<0x142, 0xa>(v, 0.0f);
  v += dpp_f<0x143, 0xc>(v, 0.0f);
  return v;
}

__device__ __forceinline__ int scan_max_dpp(int v) {
  v = max(v, dpp_i<0x111, 0xf>(v, 0));
  v = max(v, dpp_i<0x112, 0xf>(v, 0));
  v = max(v, dpp_i<0x114, 0xf>(v, 0));
  v = max(v, dpp_i<0x118, 0xf>(v, 0));
  v = max(v, dpp_i<0x142, 0xa>(v, 0));
  v = max(v, dpp_i<0x143, 0xc>(v, 0));
  return v;
}

__device__ __forceinline__ float rcpf(float x) { return __builtin_amdgcn_rcpf(x); }
__device__ __forceinline__ void wbar() { __builtin_amdgcn_wave_barrier(); }

__global__ __launch_bounds__(RPB * 64, 8) void neus_sampler(
    const float* __restrict__ org, const float* __restrict__ dirp,
    const float* __restrict__ nearp, const float* __restrict__ farp,
    float* __restrict__ out, int R) {
  __shared__ float sbA[RPB][MAXM], sdA[RPB][MAXM];
  __shared__ float sbB[RPB][MAXM], sdB[RPB][MAXM];
  __shared__ float cdfS[RPB][MAXM];
  __shared__ int   cbS[RPB][MAXM];   // phase-C rank board (129 cells)
  __shared__ int   bdS[RPB][20];     // phase-B bucket board (17 cells)

  const int wave = threadIdx.x >> 6;
  const int lane = threadIdx.x & 63;
  int ray = blockIdx.x * RPB + wave;
  const bool live = ray < R;
  if (!live) ray = R - 1;

  const float ox = org[3 * ray + 0], oy = org[3 * ray + 1], oz = org[3 * ray + 2];
  const float dx = dirp[3 * ray + 0], dy = dirp[3 * ray + 1], dz = dirp[3 * ray + 2];
  const float nr = nearp[ray], fr = farp[ray];
  const float fmn = fr - nr;

  float* sbP[2] = {sbA[wave], sbB[wave]};
  float* sdP[2] = {sdA[wave], sdB[wave]};
  float* cd = cdfS[wave];
  int*   cb = cbS[wave];
  int*   bd = bdS[wave];

  // hoisted per-lane constants
  const bool is17 = lane < 17;
  const bool is16 = lane < 16;
  const float lf1  = (float)(lane + 1);
  const float lf65 = (float)(lane + 65);
  const float uval = (float)((double)lane * ((1.0 - 1.0 / 17.0) / 16.0)) +
                     (float)(1.0 / 34.0);

  // ---- init: sbins = linspace(0,1,65); sdf at the 64 starts ----
  {
    float* sb = sbP[0];
    float* sd = sdP[0];
    for (int i = lane; i < 65; i += 64) sb[i] = (float)i * (1.0f / 64.0f);
    float s = (float)lane * (1.0f / 64.0f);
    float e = nr + s * fmn;
    float px = ox + dx * e, py = oy + dy * e, pz = oz + dz * e;
    sd[lane] = sqrtf(px * px + py * py + pz * pz) - 1.0f;
  }
  wbar();

#pragma unroll
  for (int it = 0; it < 4; ++it) {
    // inv_s with log2(e) folded in: exp(x*inv_s) == exp2(x*inv_s2)
    const float inv_s2 = 64.0f * (float)(1 << it) * 1.4426950408889634f;
    const int M = 65 + 16 * it;       // compile-time under unroll
    const bool has1 = (it > 0);
    const int m1ok = M - 66;          // chunk-1 old-element lane bound
    const float rM1 = 1.0f / (float)(M - 1);
    float* sb  = sbP[it & 1];
    float* sd  = sdP[it & 1];
    float* sb2 = sbP[(it & 1) ^ 1];
    float* sd2 = sdP[(it & 1) ^ 1];

    // ---- phase A: alpha, cumprod scan, exact weight cumsum ----
    float sA0, sA1 = 0.0f, dA0, dA1 = 0.0f;
    float cum0, cum1 = 0.0f, carryS;
    float carryT, cos_carry;
    {
      sA0 = sb[lane];
      float s1v = sb[lane + 1];
      dA0 = sd[lane];
      float sd1 = sd[lane + 1];
      float delta = (s1v - sA0) * fmn;
      float cosv = (sd1 - dA0) * rcpf(delta + 1e-5f);
      cos_carry = readlane_f(cosv, 63);
      float cosp = dpp_f<0x138, 0xf>(cosv, 0.0f);  // wave_shr:1, lane0 -> 0
      float cv = fmaxf(fminf(fminf(cosp, cosv), 0.0f), -1000.0f);
      float mid = 0.5f * (dA0 + sd1);
      float hd = cv * delta * 0.5f;
      float m2 = mid * inv_s2;
      float h2 = hd * inv_s2;
      float ea = exp2_raw(fminf(h2 - m2, 115.0f));    // exp((hd-mid)*inv_s)
      float eb = exp2_raw(fminf(-m2 - h2, 115.0f));   // exp(-(mid+hd)*inv_s)
      float t5 = 1e-5f * (1.0f + ea);
      float a = ((eb - ea) * rcpf(1.0f + eb) + t5) * rcpf(1.0f + t5);
      float alpha, q;
      if (it == 0) {  // lanes > 62 are past the last alpha
        alpha = (lane <= 62) ? a : 0.0f;
        q = (lane <= 62) ? (1.0000001f - a) : 1.0f;
      } else {        // all 64 chunk-0 intervals live
        alpha = a;
        q = 1.0000001f - a;
      }
      float S = scan_mul_dpp(q);
      float T = dpp_f<0x138, 0xf>(S, 1.0f);  // exclusive cumprod
      carryT = readlane_f(S, 63);
      float wv = alpha * T;
      float Sw = scan_add_dpp(wv);
      cum0 = Sw;
      carryS = readlane_f(Sw, 63);
    }
    if (has1) {
      sA1 = sb[lane + 64];
      float s1v = sb[lane + 65];
      dA1 = sd[lane + 64];
      float sd1 = sd[lane + 65];
      float delta = (s1v - sA1) * fmn;
      float cosv = (sd1 - dA1) * rcpf(delta + 1e-5f);
      float cosp = dpp_f<0x138, 0xf>(cosv, cos_carry);
      float cv = fmaxf(fminf(fminf(cosp, cosv), 0.0f), -1000.0f);
      float mid = 0.5f * (dA1 + sd1);
      float hd = cv * delta * 0.5f;
      float m2 = mid * inv_s2;
      float h2 = hd * inv_s2;
      float ea = exp2_raw(fminf(h2 - m2, 115.0f));
      float eb = exp2_raw(fminf(-m2 - h2, 115.0f));
      float t5 = 1e-5f * (1.0f + ea);
      float a = ((eb - ea) * rcpf(1.0f + eb) + t5) * rcpf(1.0f + t5);
      bool act = (lane <= M - 67);   // compile-time bound: intervals i <= M-3
      float alpha = act ? a : 0.0f;
      float q = act ? (1.0000001f - a) : 1.0f;
      float S = scan_mul_dpp(q);
      float T = carryT * dpp_f<0x138, 0xf>(S, 1.0f);
      float wv = alpha * T;
      float Sw = scan_add_dpp(wv);
      cum1 = carryS + Sw;
      carryS += readlane_f(Sw, 63);
    }
    float wsum = carryS;
    float pad = fmaxf(1e-5f - wsum, 0.0f);
    float wadd = pad * rM1;
    float rw = rcpf(wsum + pad);

    // cdf cells: cd[i+1] = min(1, (cum_i + (i+1)*wadd) * rw)
    float cdv0 = fminf(1.0f, (cum0 + lf1 * wadd) * rw);
    cd[lane + 1] = cdv0;
    float cdv1 = 2.0f;
    if (has1) {
      cdv1 = fminf(1.0f, (cum1 + lf65 * wadd) * rw);
      cd[lane + 65] = cdv1;  // lanes > m1ok hit cells > M-1: never read
    }
    if (lane == 0) cd[0] = 0.0f;
    if (is17) bd[lane] = 0;
    wbar();

    // ---- phase B: searchsorted via bucket-scatter + 17-lane max-scan ----
    // jm = ceil(17*cdv - 0.5) >= 0 always (cdv >= 0), so no low clamp.
    {
      int jm = (int)ceilf(fmaf(cdv0, 17.0f, -0.5f));
      if (jm < 17) bd[jm] = lane + 1;
    }
    if (has1) {
      int jm = (int)ceilf(fmaf(cdv1, 17.0f, -0.5f));
      if (lane <= m1ok && jm < 17) bd[jm] = lane + 65;
    }
    cb[lane] = 0;
    cb[lane + 64] = 0;
    wbar();

    int h;
    {
      h = is17 ? bd[lane] : 0;
      h = max(h, dpp_i<0x111, 0xf>(h, 0));
      h = max(h, dpp_i<0x112, 0xf>(h, 0));
      h = max(h, dpp_i<0x114, 0xf>(h, 0));
      h = max(h, dpp_i<0x118, 0xf>(h, 0));
      int s15 = __builtin_amdgcn_readlane(h, 15);
      if (lane == 16) h = max(h, s15);  // lane16 crosses the row boundary
      // inds = h+1, provably in [1, M-1]; below = h.
    }

    // ---- interp + closed-form merge rank for new bins ----
    float newbin = 0.0f;
    int lo = 0;
    if (is17) {
      int inds = h + 1;
      float c0 = cd[h], c1 = cd[inds];
      float b0v = sb[h], b1v = sb[inds];
      float den = c1 - c0;
      den = (den < 1e-5f) ? 1.0f : den;
      float t = fminf(fmaxf((uval - c0) * rcpf(den), 0.0f), 1.0f);
      newbin = b0v + t * (b1v - b0v);
      lo = inds;
      if (newbin == b1v && inds <= M - 2) lo = inds + 1;
    }
    float nb16 = readlane_f(newbin, 16);

    if (is16) cb[lo] = lane + 1;        // highest j wins on collision
    wbar();

    // ---- phase C: old-element shifts via 128-cell max-scan ----
    int m0 = cb[lane];
    int m1 = has1 ? cb[lane + 64] : 0;
    int c0s = scan_max_dpp(m0);
    int carryC = __builtin_amdgcn_readlane(c0s, 63);
    int c1s = max(scan_max_dpp(m1), carryC);

    {  // old elements, chunk 0 (i = lane, always <= M-2)
      int pos = lane + c0s;
      sb2[pos] = sA0;
      if (it != 3) sd2[pos] = dA0;
    }
    if (has1 && lane <= m1ok) {  // old elements, chunk 1
      int pos = lane + 64 + c1s;
      sb2[pos] = sA1;
      if (it != 3) sd2[pos] = dA1;
    }
    if (is16) {  // new elements at j + lo_j
      int pos = lane + lo;
      sb2[pos] = newbin;
      if (it != 3) {
        float e = nr + newbin * fmn;
        float px = ox + dx * e, py = oy + dy * e, pz = oz + dz * e;
        sd2[pos] = sqrtf(px * px + py * py + pz * pz) - 1.0f;
      }
    }
    if (lane == 0) sb2[M + 15] = fmaxf(sb[M - 1], nb16);
    wbar();
  }

  // ---- final: out[ray, i, :], i<128; 3x float2 per lane (coalesced) ----
  if (live) {
    float* sb = sbP[0];  // after 4 swaps, final bins are back in buffer 0
    float s0 = sb[2 * lane], s1 = sb[2 * lane + 1];
    float e0 = nr + s0 * fmn, e1 = nr + s1 * fmn;
    float ax = ox + dx * e0, ay = oy + dy * e0, az = oz + dz * e0;
    float bx = ox + dx * e1, by = oy + dy * e1, bz = oz + dz * e1;
    float2* o = (float2*)(out + (size_t)ray * 384 + (size_t)lane * 6);
    o[0] = make_float2(ax, ay);
    o[1] = make_float2(az, bx);
    o[2] = make_float2(by, bz);
  }
}

}  // namespace

extern "C" void kernel_launch(void* const* d_in, const int* in_sizes, int n_in,
                              void* d_out, int out_size, void* d_ws, size_t ws_size,
                              hipStream_t stream) {
  const float* org  = (const float*)d_in[0];
  const float* dirp = (const float*)d_in[1];
  const float* nrp  = (const float*)d_in[2];
  const float* frp  = (const float*)d_in[3];
  float* out = (float*)d_out;
  const int R = in_sizes[0] / 3;
  const int grid = (R + RPB - 1) / RPB;
  hipLaunchKernelGGL(neus_sampler, dim3(grid), dim3(RPB * 64), 0, stream,
                     org, dirp, nrp, frp, out, R);
}